// Round 4
// baseline (17653.665 us; speedup 1.0000x reference)
//
#include <hip/hip_runtime.h>
#include <cmath>

// ReservoirLayer persistent-scan kernel. B=16,T=2048,F=128,R=1024, gamma=0.95.
// 4 independent batch-groups (4 batches each) x 64 r-blocks = 256 blocks x 512 thr.
// Each block owns a 16-row slice of Wrec in VGPRs (loaded once); per step it
// computes s_next[4 batches, 16 rows]. Per-group 64-flag barrier (wave 0 polls
// 64 flags with one coalesced acquire-load + __all; s_sleep backoff). Input
// projection u_t is folded into the per-step dot (no separate GEMM, no u buf).
// Flag protocol: flag[blk]=t+2 certifies both writes AND reads of step t, so
// the 2-deep state ping-pong is race-free with one barrier per step.

constexpr int T_ = 2048, F_ = 128, R_ = 1024;
constexpr int NGRP = 4;            // batch groups
constexpr int BPG  = 4;            // batches per group
constexpr int RBLK = 16;           // r rows per block
constexpr int NRB  = R_ / RBLK;    // 64 r-blocks per group
constexpr int NBLK = NGRP * NRB;   // 256 blocks (<= CU count; all co-resident)
constexpr int NTHR = 512;          // 8 waves

constexpr size_t FLAGS_BYTES = 4096;   // [NGRP][NRB] u32, padded to 4 KiB

__global__ __launch_bounds__(NTHR) void reservoir_scan(
    const float* __restrict__ inputs,   // (B,T,F)
    const float* __restrict__ win,      // (R,F)
    const float* __restrict__ wrec,     // (R,R)
    const float* __restrict__ bias,     // (R,1)
    const float* __restrict__ rstart,   // (R,1)
    float* __restrict__ out,            // (B,T,R)
    unsigned* __restrict__ flags,       // [NGRP][NRB]
    float* __restrict__ sbuf)           // [2][NGRP][BPG][R] ping-pong state
{
  __shared__ float s_lds[BPG * R_];            // 16 KiB staged state [b][k]
  __shared__ float win_lds[RBLK * 132];        // +4 pad vs bank conflicts
  __shared__ float inp_lds[BPG * 132];
  __shared__ float part_lds[8 * BPG * RBLK];   // per-wave partials [wave][b][r]
  __shared__ float bias_lds[RBLK];

  const int tid   = threadIdx.x;
  const int bid   = blockIdx.x;
  const int bg    = bid & 3;         // batch group (stride-4 -> spread over XCDs)
  const int rg    = bid >> 2;        // 0..63 r-block
  const int r_loc = tid & 15;
  const int ks    = tid >> 4;        // 0..31 k-slice (32 k each)
  const int ks4   = ks & 3;          // k-slice within wave
  const int wave  = tid >> 6;
  const int r_g   = rg * RBLK + r_loc;

  // ---------------- one-time setup ----------------
  // Wrec slice -> VGPRs; chunk order rotated by 2*ks4 so per-step LDS reads of
  // s hit 4 distinct 16B lines per 16-lane group (16-way broadcast, 0 conflicts).
  const int c4 = 2 * ks4;
  float4 w4[8];
  {
    const float4* wr = reinterpret_cast<const float4*>(wrec + (size_t)r_g * R_ + ks * 32);
    #pragma unroll
    for (int i = 0; i < 8; ++i) w4[i] = wr[(c4 + i) & 7];
  }
  for (int i = tid; i < RBLK * F_; i += NTHR) {
    int r = i >> 7, f = i & 127;
    win_lds[r * 132 + f] = win[(size_t)(rg * RBLK + r) * F_ + f];
  }
  if (tid < RBLK) bias_lds[tid] = bias[rg * RBLK + tid];

  // init state slice into ping buffer 0 ("step 0" of the flag protocol)
  if (tid < BPG * RBLK) {
    int b = tid >> 4, r = tid & 15;
    float v = rstart[rg * RBLK + r];
    __hip_atomic_store(&sbuf[((size_t)bg * BPG + b) * R_ + rg * RBLK + r],
                       v, __ATOMIC_RELAXED, __HIP_MEMORY_SCOPE_AGENT);
  }
  __syncthreads();
  if (tid == 0)
    __hip_atomic_store(&flags[bg * NRB + rg], 1u, __ATOMIC_RELEASE, __HIP_MEMORY_SCOPE_AGENT);

  const int bi = tid >> 7, fi = tid & 127;       // staging roles for inputs
  const float* inp_ptr = inputs + (size_t)(bg * BPG + bi) * T_ * F_ + fi;

  // ---------------- scan ----------------
  for (int t = 0; t < T_; ++t) {
    // prefetch this step's input element BEFORE the poll (independent of flags)
    float iv = inp_ptr[(size_t)t * F_];

    // barrier: wait until all 64 blocks of this group finished step t-1.
    // Acquire loads: the final iteration's loads pair with each producer's
    // release store. s_sleep(1) backoff cuts spin traffic on the flag lines.
    if (tid < 64) {
      for (;;) {
        unsigned f = __hip_atomic_load(&flags[bg * NRB + tid], __ATOMIC_ACQUIRE,
                                       __HIP_MEMORY_SCOPE_AGENT);
        if (__all((int)(f >= (unsigned)(t + 1)))) break;
        __builtin_amdgcn_s_sleep(1);
      }
    }
    __syncthreads();

    // stage group state (plain float4 loads — acquire above makes them coherent)
    {
      const float4* scur4 = reinterpret_cast<const float4*>(
          sbuf + ((size_t)(t & 1) * NGRP + bg) * (BPG * R_));
      float4 v0 = scur4[tid];
      float4 v1 = scur4[NTHR + tid];
      float4* sl4 = reinterpret_cast<float4*>(s_lds);
      sl4[tid] = v0;
      sl4[NTHR + tid] = v1;
      inp_lds[bi * 132 + fi] = iv;
    }
    __syncthreads();

    // main dot: acc[b] = sum_k Wrec[r,k]*s[b,k]  (+ folded input projection)
    float acc[BPG];
    #pragma unroll
    for (int b = 0; b < BPG; ++b) {
      const float4* s4 = reinterpret_cast<const float4*>(&s_lds[b * R_ + ks * 32]);
      float a = 0.f;
      #pragma unroll
      for (int i = 0; i < 8; ++i) {
        float4 sv = s4[(c4 + i) & 7];
        float4 wv = w4[i];
        a = fmaf(wv.x, sv.x, a); a = fmaf(wv.y, sv.y, a);
        a = fmaf(wv.z, sv.z, a); a = fmaf(wv.w, sv.w, a);
      }
      if (ks < 8) {  // folded u: slices ks=0..7 cover 16 f-columns each
        const float* wrow = &win_lds[r_loc * 132 + ks * 16];
        const float* irow = &inp_lds[b * 132 + ks * 16];
        #pragma unroll
        for (int f = 0; f < 16; ++f) a = fmaf(wrow[f], irow[f], a);
      }
      acc[b] = a;
    }
    // reduce the 4 k-slices within each wave (lanes l, l^16, l^32, l^48)
    #pragma unroll
    for (int b = 0; b < BPG; ++b) {
      acc[b] += __shfl_xor(acc[b], 16, 64);
      acc[b] += __shfl_xor(acc[b], 32, 64);
    }
    if (ks4 == 0) {
      #pragma unroll
      for (int b = 0; b < BPG; ++b)
        part_lds[(wave * BPG + b) * RBLK + r_loc] = acc[b];
    }
    __syncthreads();

    // final: cross-wave reduce + tanh + blend + publish state, then release
    float snew = 0.f;
    int fb = 0, fr = 0;
    if (tid < BPG * RBLK) {
      fb = tid >> 4; fr = tid & 15;
      float pre = bias_lds[fr];
      #pragma unroll
      for (int w = 0; w < 8; ++w) pre += part_lds[(w * BPG + fb) * RBLK + fr];
      float sold = s_lds[fb * R_ + rg * RBLK + fr];
      snew = 0.05f * sold + 0.95f * tanhf(pre);   // exact f32 rounding of JAX consts
      __hip_atomic_store(&sbuf[((size_t)((t + 1) & 1) * NGRP + bg) * (size_t)(BPG * R_)
                               + (size_t)fb * R_ + rg * RBLK + fr],
                         snew, __ATOMIC_RELAXED, __HIP_MEMORY_SCOPE_AGENT);
    }
    // release: wave0's sbuf stores are same-wave (drained by the release's
    // vmcnt(0)); all waves' staging reads are ordered by the __syncthreads
    // above -> flag t+2 certifies step-t writes AND reads.
    if (tid == 0)
      __hip_atomic_store(&flags[bg * NRB + rg], (unsigned)(t + 2), __ATOMIC_RELEASE,
                         __HIP_MEMORY_SCOPE_AGENT);
    // out store off the critical path (only needs end-of-kernel visibility)
    if (tid < BPG * RBLK)
      out[(size_t)(bg * BPG + fb) * T_ * R_ + (size_t)t * R_ + rg * RBLK + fr] = snew;
    __syncthreads();   // protects s_lds reuse next iteration
  }
}

extern "C" void kernel_launch(void* const* d_in, const int* in_sizes, int n_in,
                              void* d_out, int out_size, void* d_ws, size_t ws_size,
                              hipStream_t stream) {
  const float* inputs = (const float*)d_in[0];   // (B,T,F)
  const float* win    = (const float*)d_in[1];   // (R,F)
  const float* wrec   = (const float*)d_in[2];   // (R,R)
  const float* bias   = (const float*)d_in[3];   // (R,1)
  const float* rstart = (const float*)d_in[4];   // (R,1)
  float* out = (float*)d_out;

  unsigned* flags = (unsigned*)d_ws;
  float* sbuf = (float*)((char*)d_ws + FLAGS_BYTES);
  // ws needed: 4 KiB flags + 2*4*4*1024*4 B = 132 KiB total.

  // flags must start at 0 every launch (ws is re-poisoned 0xAA by the harness)
  hipMemsetAsync(d_ws, 0, FLAGS_BYTES, stream);

  reservoir_scan<<<dim3(NBLK), dim3(NTHR), 0, stream>>>(
      inputs, win, wrec, bias, rstart, out, flags, sbuf);
}

// Round 6
// 7538.847 us; speedup vs baseline: 2.3417x; 2.3417x over previous
//
#include <hip/hip_runtime.h>
#include <cmath>

// ReservoirLayer persistent-scan kernel. B=16,T=2048,F=128,R=1024, gamma=0.95.
// 4 independent batch-groups (4 batches each) x 64 r-blocks = 256 blocks x 512 thr.
// Each block owns a 16-row slice of Wrec in VGPRs (pinned via asm); per step it
// computes s_next[4 batches, 16 rows].
//
// R6 = R5 sync redesign + asm-operand type fix (ext_vector_type for all
// asm-touched values; HIP float4 is a class and may not be a legal asm operand).
//
// Sync design (from R4 counters: 6.4% VALUBusy, 8.3us/step non-compute):
// NO acquire/release anywhere in the loop — agent-scope acq/rel lower to
// L2-wide inv/writeback ops on multi-XCD gfx950. Instead: relaxed agent
// atomics (per-access sc1 coherence) for flags+state stores, explicit
// `global_load_dwordx4 sc0 sc1` for state staging reads (stale-proof without
// any fence), and `s_waitcnt vmcnt(0)` producer-side before the flag store
// (hand-rolled release: data is ACKed at the coherence point before the flag
// is issued). Flag protocol: flag[blk]=t+2 certifies both writes AND reads of
// step t, so the 2-deep state ping-pong is race-free with one barrier/step.

typedef float f32x4 __attribute__((ext_vector_type(4)));

constexpr int T_ = 2048, F_ = 128, R_ = 1024;
constexpr int NGRP = 4;            // batch groups
constexpr int BPG  = 4;            // batches per group
constexpr int RBLK = 16;           // r rows per block
constexpr int NRB  = R_ / RBLK;    // 64 r-blocks per group
constexpr int NBLK = NGRP * NRB;   // 256 blocks (== CU count; all co-resident)
constexpr int NTHR = 512;          // 8 waves

constexpr size_t FLAGS_BYTES = 4096;   // [NGRP][NRB] u32, padded to 4 KiB

__global__ __launch_bounds__(NTHR) void reservoir_scan(
    const float* __restrict__ inputs,   // (B,T,F)
    const float* __restrict__ win,      // (R,F)
    const float* __restrict__ wrec,     // (R,R)
    const float* __restrict__ bias,     // (R,1)
    const float* __restrict__ rstart,   // (R,1)
    float* __restrict__ out,            // (B,T,R)
    unsigned* __restrict__ flags,       // [NGRP][NRB]
    float* __restrict__ sbuf)           // [2][NGRP][BPG][R] ping-pong state
{
  __shared__ float s_lds[BPG * R_];            // 16 KiB staged state [b][k]
  __shared__ float win_lds[RBLK * 129];        // stride 129 -> 2-way (free)
  __shared__ float inp_lds[BPG * 132];
  __shared__ float part_lds[8 * BPG * RBLK];   // per-wave partials [wave][b][r]
  __shared__ float bias_lds[RBLK];

  const int tid   = threadIdx.x;
  const int bid   = blockIdx.x;
  const int bg    = bid & 3;         // batch group (stride-4 -> spread over XCDs)
  const int rg    = bid >> 2;        // 0..63 r-block
  const int r_loc = tid & 15;
  const int ks    = tid >> 4;        // 0..31 k-slice (32 k each)
  const int ks4   = ks & 3;          // k-slice within wave
  const int wave  = tid >> 6;
  const int r_g   = rg * RBLK + r_loc;

  // ---------------- one-time setup ----------------
  // Wrec slice -> VGPRs; chunk order rotated by 2*ks4 so per-step LDS reads of
  // s hit 4 distinct 16B lines per 16-lane group (16-way broadcast, 0 conflicts).
  const int c4 = 2 * ks4;
  f32x4 w4[8];
  {
    const f32x4* wr = reinterpret_cast<const f32x4*>(wrec + (size_t)r_g * R_ + ks * 32);
    #pragma unroll
    for (int i = 0; i < 8; ++i) w4[i] = wr[(c4 + i) & 7];
  }
  // Pin W in VGPRs: R4 showed VGPR_Count=48 -> compiler had sunk these
  // loop-invariant loads into the t-loop (re-fetching 64KB/block/step).
  #pragma unroll
  for (int i = 0; i < 8; ++i)
    asm volatile("" : "+v"(w4[i]));

  for (int i = tid; i < RBLK * F_; i += NTHR) {
    int r = i >> 7, f = i & 127;
    win_lds[r * 129 + f] = win[(size_t)(rg * RBLK + r) * F_ + f];
  }
  if (tid < RBLK) bias_lds[tid] = bias[rg * RBLK + tid];

  // init state slice into ping buffer 0 ("step 0" of the flag protocol)
  if (tid < BPG * RBLK) {
    int b = tid >> 4, r = tid & 15;
    float v = rstart[rg * RBLK + r];
    __hip_atomic_store(&sbuf[((size_t)bg * BPG + b) * R_ + rg * RBLK + r],
                       v, __ATOMIC_RELAXED, __HIP_MEMORY_SCOPE_AGENT);
  }
  __syncthreads();
  if (tid == 0) {
    asm volatile("s_waitcnt vmcnt(0)" ::: "memory");   // init stores are wave0's
    __hip_atomic_store(&flags[bg * NRB + rg], 1u, __ATOMIC_RELAXED,
                       __HIP_MEMORY_SCOPE_AGENT);
  }

  const int bi = tid >> 7, fi = tid & 127;       // staging roles for inputs
  const float* inp_ptr = inputs + (size_t)(bg * BPG + bi) * T_ * F_ + fi;

  // ---------------- scan ----------------
  for (int t = 0; t < T_; ++t) {
    // prefetch this step's input element BEFORE the poll (independent of flags)
    float iv = inp_ptr[(size_t)t * F_];

    // barrier: wait until all 64 blocks of this group finished step t-1.
    // RELAXED polls (sc1-coherent loads, NO per-iteration cache invalidate).
    if (tid < 64) {
      for (;;) {
        unsigned f = __hip_atomic_load(&flags[bg * NRB + tid], __ATOMIC_RELAXED,
                                       __HIP_MEMORY_SCOPE_AGENT);
        if (__all((int)(f >= (unsigned)(t + 1)))) break;
        __builtin_amdgcn_s_sleep(1);
      }
    }
    __syncthreads();

    // stage group state with explicitly coherent loads (sc0 sc1 -> fetch from
    // the coherence point, immune to stale L1/L2 — no acquire fence needed).
    {
      const f32x4* scur4 = reinterpret_cast<const f32x4*>(
          sbuf + ((size_t)(t & 1) * NGRP + bg) * (BPG * R_));
      const f32x4* p0 = scur4 + tid;
      const f32x4* p1 = scur4 + NTHR + tid;
      f32x4 v0, v1;
      asm volatile("global_load_dwordx4 %0, %1, off sc0 sc1"
                   : "=&v"(v0) : "v"(p0) : "memory");
      asm volatile("global_load_dwordx4 %0, %1, off sc0 sc1"
                   : "=&v"(v1) : "v"(p1) : "memory");
      asm volatile("s_waitcnt vmcnt(0)" ::: "memory");
      __builtin_amdgcn_sched_barrier(0);   // rule #18: nothing hoists past the wait
      f32x4* sl4 = reinterpret_cast<f32x4*>(s_lds);
      sl4[tid] = v0;
      sl4[NTHR + tid] = v1;
      inp_lds[bi * 132 + fi] = iv;
    }
    __syncthreads();

    // main dot: acc[b] = sum_k Wrec[r,k]*s[b,k]  (+ folded input projection)
    float acc[BPG];
    #pragma unroll
    for (int b = 0; b < BPG; ++b) {
      const f32x4* s4 = reinterpret_cast<const f32x4*>(&s_lds[b * R_ + ks * 32]);
      float a = 0.f;
      #pragma unroll
      for (int i = 0; i < 8; ++i) {
        f32x4 sv = s4[(c4 + i) & 7];
        f32x4 wv = w4[i];
        a = fmaf(wv.x, sv.x, a); a = fmaf(wv.y, sv.y, a);
        a = fmaf(wv.z, sv.z, a); a = fmaf(wv.w, sv.w, a);
      }
      if (ks < 8) {  // folded u: slices ks=0..7 cover 16 f-columns each
        const float* wrow = &win_lds[r_loc * 129 + ks * 16];
        const float* irow = &inp_lds[b * 132 + ks * 16];
        #pragma unroll
        for (int f = 0; f < 16; ++f) a = fmaf(wrow[f], irow[f], a);
      }
      acc[b] = a;
    }
    // reduce the 4 k-slices within each wave (lanes l, l^16, l^32, l^48)
    #pragma unroll
    for (int b = 0; b < BPG; ++b) {
      acc[b] += __shfl_xor(acc[b], 16, 64);
      acc[b] += __shfl_xor(acc[b], 32, 64);
    }
    if (ks4 == 0) {
      #pragma unroll
      for (int b = 0; b < BPG; ++b)
        part_lds[(wave * BPG + b) * RBLK + r_loc] = acc[b];
    }
    __syncthreads();

    // final: cross-wave reduce + tanh + blend + publish state, then flag
    float snew = 0.f;
    int fb = 0, fr = 0;
    if (tid < BPG * RBLK) {
      fb = tid >> 4; fr = tid & 15;
      float pre = bias_lds[fr];
      #pragma unroll
      for (int w = 0; w < 8; ++w) pre += part_lds[(w * BPG + fb) * RBLK + fr];
      float sold = s_lds[fb * R_ + rg * RBLK + fr];
      snew = 0.05f * sold + 0.95f * tanhf(pre);   // exact f32 rounding of JAX consts
      __hip_atomic_store(&sbuf[((size_t)((t + 1) & 1) * NGRP + bg) * (size_t)(BPG * R_)
                               + (size_t)fb * R_ + rg * RBLK + fr],
                         snew, __ATOMIC_RELAXED, __HIP_MEMORY_SCOPE_AGENT);
    }
    // hand-rolled release: sbuf stores are wave0's; vmcnt(0) completes them at
    // the coherence point before the (relaxed, sc1) flag store is issued.
    // Staging reads of this buffer were ordered by the __syncthreads above,
    // so flag t+2 certifies step-t writes AND reads.
    if (tid == 0) {
      asm volatile("s_waitcnt vmcnt(0)" ::: "memory");
      __hip_atomic_store(&flags[bg * NRB + rg], (unsigned)(t + 2), __ATOMIC_RELAXED,
                         __HIP_MEMORY_SCOPE_AGENT);
    }
    // out store off the critical path (only needs end-of-kernel visibility)
    if (tid < BPG * RBLK)
      out[(size_t)(bg * BPG + fb) * T_ * R_ + (size_t)t * R_ + rg * RBLK + fr] = snew;
    __syncthreads();   // protects s_lds reuse next iteration
  }
}

extern "C" void kernel_launch(void* const* d_in, const int* in_sizes, int n_in,
                              void* d_out, int out_size, void* d_ws, size_t ws_size,
                              hipStream_t stream) {
  const float* inputs = (const float*)d_in[0];   // (B,T,F)
  const float* win    = (const float*)d_in[1];   // (R,F)
  const float* wrec   = (const float*)d_in[2];   // (R,R)
  const float* bias   = (const float*)d_in[3];   // (R,1)
  const float* rstart = (const float*)d_in[4];   // (R,1)
  float* out = (float*)d_out;

  unsigned* flags = (unsigned*)d_ws;
  float* sbuf = (float*)((char*)d_ws + FLAGS_BYTES);
  // ws needed: 4 KiB flags + 2*4*4*1024*4 B = 132 KiB total.

  // flags must start at 0 every launch (ws is re-poisoned 0xAA by the harness)
  hipMemsetAsync(d_ws, 0, FLAGS_BYTES, stream);

  reservoir_scan<<<dim3(NBLK), dim3(NTHR), 0, stream>>>(
      inputs, win, wrec, bias, rstart, out, flags, sbuf);
}